// Round 11
// baseline (329.216 us; speedup 1.0000x reference)
//
#include <hip/hip_runtime.h>
#include <hip/hip_cooperative_groups.h>
#include <hip/hip_bf16.h>

#define B_ 16
#define C_ 128
#define D_ 256

namespace cg = cooperative_groups;

typedef unsigned int uint32;
typedef unsigned short u16;
typedef __attribute__((ext_vector_type(8))) short s8v;   // 8 bf16 = 4 VGPR
typedef __attribute__((ext_vector_type(4))) float f4v;   // MFMA acc

__device__ __forceinline__ u16 bfu(float x) {
  union { __hip_bfloat16 h; u16 s; } u;
  u.h = __float2bfloat16(x);
  return u.s;
}
__device__ __forceinline__ float2 bf2x(uint32 x) {
  return make_float2(__uint_as_float(x << 16), __uint_as_float(x & 0xffff0000u));
}

// ---------------------------------------------------------------------------
// ONE cooperative kernel, 512 blocks x 256 thr, __launch_bounds__(256,2):
// guaranteed 2 blocks/CU co-resident (LDS 33KB/CU, VGPR<=256). Phases:
//  P0 prep (785 tasks, task-loop):
//      t<512: hbT[16][256][128]=bf16(h^T);  512..640: w1t[512n][256k];
//      640..768: wcatT[256n][512k] (betas folded); 768..784: amT; 784: bcat
//  P1 k1 (4096 tiles, 2/wave): [P|Q](2048x512) = bf16(h) @ w1t^T (+b1)
//  P2 k2 (1024 tiles, 2/block): SA_T = bf16(sigmoid(relu-dot)*Aa)
//  P3 k3+k4 (128 blocks): a_t/m_t -> swizzled LDS tile -> z (atcat never global)
// ---------------------------------------------------------------------------
__global__ __launch_bounds__(256, 2) void kfused(
    const float* __restrict__ h,  const float* __restrict__ Aa,
    const float* __restrict__ Am, const float* __restrict__ W1,
    const float* __restrict__ b1, const float* __restrict__ W2,
    const float* __restrict__ b2, const float* __restrict__ Wa,
    const float* __restrict__ ba, const float* __restrict__ Wm,
    const float* __restrict__ bm, const float* __restrict__ be1,
    const float* __restrict__ be2, const float* __restrict__ be3,
    float* __restrict__ z,
    u16* __restrict__ w1t, u16* __restrict__ wcatT, u16* __restrict__ amT,
    float* __restrict__ bcat, u16* __restrict__ hbT,
    u16* __restrict__ P, u16* __restrict__ Q, u16* __restrict__ SA) {
  cg::grid_group grid = cg::this_grid();
  const int bid = blockIdx.x;
  const int tid = threadIdx.x;

  __shared__ union SmT {
    struct { uint32 Pl[16][130]; uint32 Ql[16][130]; } s2;  // 16.6 KB (P2)
    u16 at[16 * 512];                                       // 16 KB  (P3)
  } sm;

  // ------------------------------ P0: prep ---------------------------------
  for (int t = bid; t < 785; t += 512) {
    if (t < 512) {               // hbT = bf16(h^T per batch)
      const int i4 = (t * 256 + tid) * 4;
      const int b = i4 >> 15, r = i4 & 32767, d = r >> 7, u0 = r & 127;
      ushort4 o;
      o.x = bfu(h[(b * C_ + u0 + 0) * D_ + d]);
      o.y = bfu(h[(b * C_ + u0 + 1) * D_ + d]);
      o.z = bfu(h[(b * C_ + u0 + 2) * D_ + d]);
      o.w = bfu(h[(b * C_ + u0 + 3) * D_ + d]);
      *(ushort4*)(hbT + i4) = o;
    } else if (t < 640) {        // w1t[512 n][256 k]
      const int i4 = ((t - 512) * 256 + tid) * 4;
      const int n = i4 >> 8, k0 = i4 & 255;
      float x0, x1, x2, x3;
      if (n < 256) {
        x0 = W1[(k0 + 0) * 256 + n]; x1 = W1[(k0 + 1) * 256 + n];
        x2 = W1[(k0 + 2) * 256 + n]; x3 = W1[(k0 + 3) * 256 + n];
      } else {
        const int nn = n - 256;
        x0 = W1[(256 + k0 + 0) * 256 + nn]; x1 = W1[(256 + k0 + 1) * 256 + nn];
        x2 = W1[(256 + k0 + 2) * 256 + nn]; x3 = W1[(256 + k0 + 3) * 256 + nn];
      }
      ushort4 o; o.x = bfu(x0); o.y = bfu(x1); o.z = bfu(x2); o.w = bfu(x3);
      *(ushort4*)(w1t + i4) = o;
    } else if (t < 768) {        // wcatT[256 n][512 k]
      const float b2v = be2[0], b3v = be3[0];
      const int i4 = ((t - 640) * 256 + tid) * 4;
      const int n = i4 >> 9, k0 = i4 & 511;
      float x0, x1, x2, x3;
      if (k0 < 256) {
        x0 = b2v * Wa[(k0 + 0) * 256 + n]; x1 = b2v * Wa[(k0 + 1) * 256 + n];
        x2 = b2v * Wa[(k0 + 2) * 256 + n]; x3 = b2v * Wa[(k0 + 3) * 256 + n];
      } else {
        const int kk = k0 - 256;
        x0 = b3v * Wm[(kk + 0) * 256 + n]; x1 = b3v * Wm[(kk + 1) * 256 + n];
        x2 = b3v * Wm[(kk + 2) * 256 + n]; x3 = b3v * Wm[(kk + 3) * 256 + n];
      }
      ushort4 o; o.x = bfu(x0); o.y = bfu(x1); o.z = bfu(x2); o.w = bfu(x3);
      *(ushort4*)(wcatT + i4) = o;
    } else if (t < 784) {        // amT[128 v][128 u]
      const int i4 = ((t - 768) * 256 + tid) * 4;
      const int v = i4 >> 7, u0 = i4 & 127;
      ushort4 o;
      o.x = bfu(Am[(u0 + 0) * C_ + v]);
      o.y = bfu(Am[(u0 + 1) * C_ + v]);
      o.z = bfu(Am[(u0 + 2) * C_ + v]);
      o.w = bfu(Am[(u0 + 3) * C_ + v]);
      *(ushort4*)(amT + i4) = o;
    } else {                     // bcat
      bcat[tid] = be2[0] * ba[tid] + be3[0] * bm[tid];
    }
  }
  grid.sync();

  // ------------------------------ P1: k1 -----------------------------------
  {
    const int lane = tid & 63;
    const int lr = lane & 15, lk = lane >> 4;
#pragma unroll
    for (int rep = 0; rep < 2; ++rep) {
      const int w = bid * 4 + (tid >> 6) + rep * 2048;   // 0..4095
      const int nt = w & 31, mt = w >> 5;
      const int row0 = mt * 16, col0 = nt * 16;
      const float* ap = h + (row0 + lr) * D_ + lk * 8;
      const u16* bp = w1t + (col0 + lr) * D_ + lk * 8;
      f4v acc = {0.f, 0.f, 0.f, 0.f};
#pragma unroll
      for (int ks = 0; ks < 8; ++ks) {
        const float4 a0 = *(const float4*)(ap + ks * 32);
        const float4 a1 = *(const float4*)(ap + ks * 32 + 4);
        union { s8v v; u16 u[8]; } af;
        af.u[0] = bfu(a0.x); af.u[1] = bfu(a0.y); af.u[2] = bfu(a0.z); af.u[3] = bfu(a0.w);
        af.u[4] = bfu(a1.x); af.u[5] = bfu(a1.y); af.u[6] = bfu(a1.z); af.u[7] = bfu(a1.w);
        const s8v bf = *(const s8v*)(bp + ks * 32);
        acc = __builtin_amdgcn_mfma_f32_16x16x32_bf16(af.v, bf, acc, 0, 0, 0);
      }
      const int col = col0 + lr;
      if (col0 < 256) {
#pragma unroll
        for (int r = 0; r < 4; ++r)
          P[(row0 + lk * 4 + r) * D_ + col] = bfu(acc[r]);
      } else {
        const float bb = b1[col - 256];
#pragma unroll
        for (int r = 0; r < 4; ++r)
          Q[(row0 + lk * 4 + r) * D_ + (col - 256)] = bfu(acc[r] + bb);
      }
    }
  }
  grid.sync();

  // ------------------------------ P2: k2 -----------------------------------
  {
    const float4* __restrict__ w4 = (const float4*)W2;
#pragma unroll
    for (int rep = 0; rep < 2; ++rep) {
      const int t = bid + rep * 512;                 // 0..1023
      const int b = t >> 6;
      const int u0 = ((t >> 3) & 7) * 16;
      const int v0 = (t & 7) * 16;
      const uint32* Pg = (const uint32*)(P + (b * C_ + u0) * D_);
      const uint32* Qg = (const uint32*)(Q + (b * C_ + v0) * D_);
      {  // 16 rows x 128 uint32 each: per thread 2 halves x uint4
        const int r = tid >> 5;            // 0..7
        const int c4 = (tid & 31) * 4;     // 0,4,...,124
#pragma unroll
        for (int half = 0; half < 2; ++half) {
          const int rr = r + half * 8;
          const uint4 pv = *(const uint4*)&Pg[rr * 128 + c4];
          const uint4 qv = *(const uint4*)&Qg[rr * 128 + c4];
          *(uint2*)&sm.s2.Pl[rr][c4]     = make_uint2(pv.x, pv.y);
          *(uint2*)&sm.s2.Pl[rr][c4 + 2] = make_uint2(pv.z, pv.w);
          *(uint2*)&sm.s2.Ql[rr][c4]     = make_uint2(qv.x, qv.y);
          *(uint2*)&sm.s2.Ql[rr][c4 + 2] = make_uint2(qv.z, qv.w);
        }
      }
      __syncthreads();
      const int ul = tid & 15;
      const int vl = tid >> 4;
      float a0 = 0.f, a1 = 0.f;
#pragma unroll 8
      for (int kk = 0; kk < 128; kk += 2) {
        const uint2 pu = *(const uint2*)&sm.s2.Pl[ul][kk];
        const uint2 qu = *(const uint2*)&sm.s2.Ql[vl][kk];
        const float4 wv = w4[kk >> 1];
        const float2 p0 = bf2x(pu.x), p1 = bf2x(pu.y);
        const float2 q0 = bf2x(qu.x), q1 = bf2x(qu.y);
        a0 = fmaf(fmaxf(p0.x + q0.x, 0.f), wv.x, a0);
        a0 = fmaf(fmaxf(p0.y + q0.y, 0.f), wv.y, a0);
        a1 = fmaf(fmaxf(p1.x + q1.x, 0.f), wv.z, a1);
        a1 = fmaf(fmaxf(p1.y + q1.y, 0.f), wv.w, a1);
      }
      const float s = 1.f / (1.f + __expf(-(a0 + a1 + b2[0])));
      const int u = u0 + ul, v = v0 + vl;
      SA[b * C_ * C_ + v * C_ + u] = bfu(s * Aa[u * C_ + v]);
      __syncthreads();   // all reads done before next rep restages LDS
    }
  }
  grid.sync();

  // ------------------------------ P3: k3+k4 --------------------------------
  if (bid < 128) {
    const int bt = bid >> 3;
    const int v0 = (bid & 7) * 16;
    const int lane = tid & 63, widx = tid >> 6;
    const int lr = lane & 15, lk = lane >> 4;
    // ---- k3: 4 d-tiles/wave -> swizzled LDS atcat tile [16][512] bf16 ----
#pragma unroll
    for (int i = 0; i < 4; ++i) {
      const int d0 = (widx * 4 + i) * 16;
      const u16* sap = SA + (bt * C_ + v0 + lr) * C_ + lk * 8;
      const u16* a2p = amT + (v0 + lr) * C_ + lk * 8;
      const u16* bp  = hbT + (bt * D_ + d0 + lr) * C_ + lk * 8;
      f4v acca = {0.f, 0.f, 0.f, 0.f}, accm = {0.f, 0.f, 0.f, 0.f};
#pragma unroll
      for (int ks = 0; ks < 4; ++ks) {
        const s8v a1 = *(const s8v*)(sap + ks * 32);
        const s8v a2 = *(const s8v*)(a2p + ks * 32);
        const s8v bf = *(const s8v*)(bp + ks * 32);
        acca = __builtin_amdgcn_mfma_f32_16x16x32_bf16(a1, bf, acca, 0, 0, 0);
        accm = __builtin_amdgcn_mfma_f32_16x16x32_bf16(a2, bf, accm, 0, 0, 0);
      }
      const int d = d0 + lr;
#pragma unroll
      for (int r = 0; r < 4; ++r) {
        const int R = lk * 4 + r;
        const int grow = bt * C_ + v0 + R;
        const float hv = h[grow * D_ + d];
        const int swz = (R & 7) << 4;
        *(u16*)((char*)sm.at + R * 1024 + ((d * 2) ^ swz)) = bfu(acca[r]);
        *(u16*)((char*)sm.at + R * 1024 + (((256 + d) * 2) ^ swz)) = bfu(accm[r] * hv);
      }
    }
    __syncthreads();
    // ---- k4: 4 col-tiles/wave: z = at(16x512) @ wcatT^T + b1*h + bcat ----
    const float b1v = be1[0];
#pragma unroll
    for (int i = 0; i < 4; ++i) {
      const int col0 = (widx * 4 + i) * 16;
      const u16* bp = wcatT + (col0 + lr) * 512 + lk * 8;
      f4v acc = {0.f, 0.f, 0.f, 0.f};
#pragma unroll
      for (int ks = 0; ks < 16; ++ks) {
        const int boff = lr * 1024 + ((ks * 64 + lk * 16) ^ ((lr & 7) << 4));
        const s8v af = *(const s8v*)((char*)sm.at + boff);
        const s8v bf = *(const s8v*)(bp + ks * 32);
        acc = __builtin_amdgcn_mfma_f32_16x16x32_bf16(af, bf, acc, 0, 0, 0);
      }
      const int col = col0 + lr;
      const float bc = bcat[col];
#pragma unroll
      for (int r = 0; r < 4; ++r) {
        const int row = bt * C_ + v0 + lk * 4 + r;
        z[row * D_ + col] = acc[r] + b1v * h[row * D_ + col] + bc;
      }
    }
  }
}

extern "C" void kernel_launch(void* const* d_in, const int* in_sizes, int n_in,
                              void* d_out, int out_size, void* d_ws, size_t ws_size,
                              hipStream_t stream) {
  const float* h   = (const float*)d_in[0];
  const float* Aa  = (const float*)d_in[1];
  const float* Am  = (const float*)d_in[2];
  const float* W1  = (const float*)d_in[3];
  const float* b1  = (const float*)d_in[4];
  const float* W2  = (const float*)d_in[5];
  const float* b2  = (const float*)d_in[6];
  const float* Wa  = (const float*)d_in[7];
  const float* ba  = (const float*)d_in[8];
  const float* Wm  = (const float*)d_in[9];
  const float* bm  = (const float*)d_in[10];
  const float* be1 = (const float*)d_in[11];
  const float* be2 = (const float*)d_in[12];
  const float* be3 = (const float*)d_in[13];
  float* z = (float*)d_out;

  char* wsb = (char*)d_ws;
  u16*   w1t   = (u16*)(wsb);                             // 256 KB
  u16*   wcatT = (u16*)(wsb + (256 << 10));               // 256 KB
  u16*   amT   = (u16*)(wsb + (512 << 10));               // 32 KB
  float* bcat  = (float*)(wsb + (544 << 10));             // 1 KB
  u16*   hbT   = (u16*)(wsb + (1 << 20));                 // 1 MB
  u16*   P     = (u16*)(wsb + (2 << 20));                 // 1 MB
  u16*   Q     = (u16*)(wsb + (3 << 20));                 // 1 MB
  u16*   SA    = (u16*)(wsb + (4 << 20));                 // 512 KB [b][v][u]

  void* args[] = {
    (void*)&h, (void*)&Aa, (void*)&Am, (void*)&W1, (void*)&b1, (void*)&W2,
    (void*)&b2, (void*)&Wa, (void*)&ba, (void*)&Wm, (void*)&bm, (void*)&be1,
    (void*)&be2, (void*)&be3, (void*)&z, (void*)&w1t, (void*)&wcatT,
    (void*)&amT, (void*)&bcat, (void*)&hbT, (void*)&P, (void*)&Q, (void*)&SA,
  };
  hipLaunchCooperativeKernel((const void*)kfused, dim3(512), dim3(256),
                             args, 0, stream);
}

// Round 12
// 121.976 us; speedup vs baseline: 2.6990x; 2.6990x over previous
//
#include <hip/hip_runtime.h>
#include <hip/hip_bf16.h>

#define B_ 16
#define C_ 128
#define D_ 256

typedef unsigned int uint32;
typedef unsigned short u16;
typedef __attribute__((ext_vector_type(8))) short s8v;   // 8 bf16 = 4 VGPR
typedef __attribute__((ext_vector_type(4))) float f4v;   // MFMA acc

__device__ __forceinline__ u16 bfu(float x) {
  union { __hip_bfloat16 h; u16 s; } u;
  u.h = __float2bfloat16(x);
  return u.s;
}
__device__ __forceinline__ float2 bf2x(uint32 x) {
  return make_float2(__uint_as_float(x << 16), __uint_as_float(x & 0xffff0000u));
}

// ---------------------------------------------------------------------------
// PREP (785 blocks):
//  [0,512):   hbT[16][256][128] = bf16(h^T per batch)   (k3 B operand)
//  [512,640): w1t[512 n][256 k]                          (k1 B operand)
//  [640,768): wcatT[256 n][512 k] (betas folded)         (k4 B operand)
//  [768,784): amT[128 v][128 u]                          (k3 A2 operand)
//  784:       bcat[256] = b2*ba + b3*bm (fp32)
// ---------------------------------------------------------------------------
__global__ __launch_bounds__(256) void kprep(const float* __restrict__ h,
    const float* __restrict__ W1, const float* __restrict__ Wa,
    const float* __restrict__ Wm, const float* __restrict__ Am,
    const float* __restrict__ ba, const float* __restrict__ bm,
    const float* __restrict__ be2, const float* __restrict__ be3,
    u16* __restrict__ hbT, u16* __restrict__ w1t,
    u16* __restrict__ wcatT, u16* __restrict__ amT, float* __restrict__ bcat) {
  const int blk = blockIdx.x;
  const int tid = threadIdx.x;
  if (blk < 512) {               // hbT
    const int i4 = (blk * 256 + tid) * 4;
    const int b = i4 >> 15, r = i4 & 32767, d = r >> 7, u0 = r & 127;
    ushort4 o;
    o.x = bfu(h[(b * C_ + u0 + 0) * D_ + d]);
    o.y = bfu(h[(b * C_ + u0 + 1) * D_ + d]);
    o.z = bfu(h[(b * C_ + u0 + 2) * D_ + d]);
    o.w = bfu(h[(b * C_ + u0 + 3) * D_ + d]);
    *(ushort4*)(hbT + i4) = o;
  } else if (blk < 640) {        // w1t[512 n][256 k]
    const int i4 = ((blk - 512) * 256 + tid) * 4;
    const int n = i4 >> 8, k0 = i4 & 255;
    float x0, x1, x2, x3;
    if (n < 256) {
      x0 = W1[(k0 + 0) * 256 + n]; x1 = W1[(k0 + 1) * 256 + n];
      x2 = W1[(k0 + 2) * 256 + n]; x3 = W1[(k0 + 3) * 256 + n];
    } else {
      const int nn = n - 256;
      x0 = W1[(256 + k0 + 0) * 256 + nn]; x1 = W1[(256 + k0 + 1) * 256 + nn];
      x2 = W1[(256 + k0 + 2) * 256 + nn]; x3 = W1[(256 + k0 + 3) * 256 + nn];
    }
    ushort4 o; o.x = bfu(x0); o.y = bfu(x1); o.z = bfu(x2); o.w = bfu(x3);
    *(ushort4*)(w1t + i4) = o;
  } else if (blk < 768) {        // wcatT[256 n][512 k]
    const float b2v = be2[0], b3v = be3[0];
    const int i4 = ((blk - 640) * 256 + tid) * 4;
    const int n = i4 >> 9, k0 = i4 & 511;
    float x0, x1, x2, x3;
    if (k0 < 256) {
      x0 = b2v * Wa[(k0 + 0) * 256 + n]; x1 = b2v * Wa[(k0 + 1) * 256 + n];
      x2 = b2v * Wa[(k0 + 2) * 256 + n]; x3 = b2v * Wa[(k0 + 3) * 256 + n];
    } else {
      const int kk = k0 - 256;
      x0 = b3v * Wm[(kk + 0) * 256 + n]; x1 = b3v * Wm[(kk + 1) * 256 + n];
      x2 = b3v * Wm[(kk + 2) * 256 + n]; x3 = b3v * Wm[(kk + 3) * 256 + n];
    }
    ushort4 o; o.x = bfu(x0); o.y = bfu(x1); o.z = bfu(x2); o.w = bfu(x3);
    *(ushort4*)(wcatT + i4) = o;
  } else if (blk < 784) {        // amT[128 v][128 u]
    const int i4 = ((blk - 768) * 256 + tid) * 4;
    const int v = i4 >> 7, u0 = i4 & 127;
    ushort4 o;
    o.x = bfu(Am[(u0 + 0) * C_ + v]);
    o.y = bfu(Am[(u0 + 1) * C_ + v]);
    o.z = bfu(Am[(u0 + 2) * C_ + v]);
    o.w = bfu(Am[(u0 + 3) * C_ + v]);
    *(ushort4*)(amT + i4) = o;
  } else {                       // bcat
    bcat[tid] = be2[0] * ba[tid] + be3[0] * bm[tid];
  }
}

// ---------------------------------------------------------------------------
// K1 (MFMA): [P|Q](2048 x 512) = bf16(h) @ w1t^T ; Q += b1.
// A fragment converted fp32->bf16 in-register (no hb intermediate).
// 4096 waves (128 mt x 32 nt), 16x16 tile, K=256 -> 8 MFMA. 1024 blocks.
// ---------------------------------------------------------------------------
__global__ __launch_bounds__(256) void k1_mfma(const float* __restrict__ h,
    const u16* __restrict__ w1t, const float* __restrict__ b1,
    u16* __restrict__ P, u16* __restrict__ Q) {
  const int lane = threadIdx.x & 63;
  const int w = blockIdx.x * 4 + (threadIdx.x >> 6);   // 0..4095
  const int nt = w & 31, mt = w >> 5;
  const int row0 = mt * 16, col0 = nt * 16;
  const int lr = lane & 15, lk = lane >> 4;
  const float* ap = h + (row0 + lr) * D_ + lk * 8;
  const u16* bp = w1t + (col0 + lr) * D_ + lk * 8;
  f4v acc = {0.f, 0.f, 0.f, 0.f};
#pragma unroll
  for (int ks = 0; ks < 8; ++ks) {
    const float4 a0 = *(const float4*)(ap + ks * 32);
    const float4 a1 = *(const float4*)(ap + ks * 32 + 4);
    union { s8v v; u16 u[8]; } af;
    af.u[0] = bfu(a0.x); af.u[1] = bfu(a0.y); af.u[2] = bfu(a0.z); af.u[3] = bfu(a0.w);
    af.u[4] = bfu(a1.x); af.u[5] = bfu(a1.y); af.u[6] = bfu(a1.z); af.u[7] = bfu(a1.w);
    const s8v bf = *(const s8v*)(bp + ks * 32);
    acc = __builtin_amdgcn_mfma_f32_16x16x32_bf16(af.v, bf, acc, 0, 0, 0);
  }
  const int col = col0 + lr;
  if (col0 < 256) {
#pragma unroll
    for (int r = 0; r < 4; ++r)
      P[(row0 + lk * 4 + r) * D_ + col] = bfu(acc[r]);
  } else {
    const float bb = b1[col - 256];
#pragma unroll
    for (int r = 0; r < 4; ++r)
      Q[(row0 + lk * 4 + r) * D_ + (col - 256)] = bfu(acc[r] + bb);
  }
}

// ---------------------------------------------------------------------------
// K2 (VALU, irreducible relu-dot):
// SA_T[b,v,u] = bf16( sigmoid( sum_k relu(P[b,u,k]+Q[b,v,k])*W2[k]+b2 ) * Aa[u,v] )
// 16x16 uv-tile; P/Q packed bf16 in LDS (pad 130). Grid (8,8,16)=1024 blocks.
// ---------------------------------------------------------------------------
__global__ __launch_bounds__(256) void k2_s(const u16* __restrict__ P,
    const u16* __restrict__ Q, const float* __restrict__ W2,
    const float* __restrict__ b2, const float* __restrict__ Aa,
    u16* __restrict__ SA) {
  const int b = blockIdx.z;
  const int u0 = blockIdx.x * 16;
  const int v0 = blockIdx.y * 16;
  const int tid = threadIdx.x;
  __shared__ uint32 Pl[16][130];
  __shared__ uint32 Ql[16][130];
  const uint32* Pg = (const uint32*)(P + (b * C_ + u0) * D_);
  const uint32* Qg = (const uint32*)(Q + (b * C_ + v0) * D_);
  {
    const int r = tid >> 5;            // 0..7
    const int c4 = (tid & 31) * 4;     // 0,4,...,124
#pragma unroll
    for (int half = 0; half < 2; ++half) {
      const int rr = r + half * 8;
      const uint4 pv = *(const uint4*)&Pg[rr * 128 + c4];
      const uint4 qv = *(const uint4*)&Qg[rr * 128 + c4];
      *(uint2*)&Pl[rr][c4]     = make_uint2(pv.x, pv.y);
      *(uint2*)&Pl[rr][c4 + 2] = make_uint2(pv.z, pv.w);
      *(uint2*)&Ql[rr][c4]     = make_uint2(qv.x, qv.y);
      *(uint2*)&Ql[rr][c4 + 2] = make_uint2(qv.z, qv.w);
    }
  }
  __syncthreads();
  const int ul = tid & 15;
  const int vl = tid >> 4;
  const float4* __restrict__ w4 = (const float4*)W2;
  float a0 = 0.f, a1 = 0.f;
#pragma unroll 8
  for (int kk = 0; kk < 128; kk += 2) {
    const uint2 pu = *(const uint2*)&Pl[ul][kk];
    const uint2 qu = *(const uint2*)&Ql[vl][kk];
    const float4 wv = w4[kk >> 1];
    const float2 p0 = bf2x(pu.x), p1 = bf2x(pu.y);
    const float2 q0 = bf2x(qu.x), q1 = bf2x(qu.y);
    a0 = fmaf(fmaxf(p0.x + q0.x, 0.f), wv.x, a0);
    a0 = fmaf(fmaxf(p0.y + q0.y, 0.f), wv.y, a0);
    a1 = fmaf(fmaxf(p1.x + q1.x, 0.f), wv.z, a1);
    a1 = fmaf(fmaxf(p1.y + q1.y, 0.f), wv.w, a1);
  }
  const float s = 1.f / (1.f + __expf(-(a0 + a1 + b2[0])));
  const int u = u0 + ul, v = v0 + vl;
  SA[b * C_ * C_ + v * C_ + u] = bfu(s * Aa[u * C_ + v]);
}

// ---------------------------------------------------------------------------
// K34 (fused k3+k4, MFMA): per 16-row tile (128 blocks x 512 thr, 8 waves):
//  k3: a_t = SA_T @ h ; m_t = (AmT @ h) .* h  -> swizzled LDS tile [16][512]
//  k4: z = at @ wcatT^T + beta1*h + bcat      (atcat never hits global)
// Each wave: 2 d-tiles (k3) + 2 col-tiles (k4).
// ---------------------------------------------------------------------------
__global__ __launch_bounds__(512) void k34_mfma(const u16* __restrict__ SA,
    const u16* __restrict__ amT, const u16* __restrict__ hbT,
    const u16* __restrict__ wcatT, const float* __restrict__ bcat,
    const float* __restrict__ h, const float* __restrict__ be1,
    float* __restrict__ z) {
  const int bid = blockIdx.x;
  const int tid = threadIdx.x;
  const int bt = bid >> 3;
  const int v0 = (bid & 7) * 16;
  const int lane = tid & 63, widx = tid >> 6;    // widx 0..7
  const int lr = lane & 15, lk = lane >> 4;
  __shared__ u16 at[16 * 512];                   // swizzled [16][512] bf16

  // ---- k3: 2 d-tiles/wave ----
#pragma unroll
  for (int i = 0; i < 2; ++i) {
    const int d0 = (widx * 2 + i) * 16;
    const u16* sap = SA + (bt * C_ + v0 + lr) * C_ + lk * 8;
    const u16* a2p = amT + (v0 + lr) * C_ + lk * 8;
    const u16* bp  = hbT + (bt * D_ + d0 + lr) * C_ + lk * 8;
    f4v acca = {0.f, 0.f, 0.f, 0.f}, accm = {0.f, 0.f, 0.f, 0.f};
#pragma unroll
    for (int ks = 0; ks < 4; ++ks) {
      const s8v a1 = *(const s8v*)(sap + ks * 32);
      const s8v a2 = *(const s8v*)(a2p + ks * 32);
      const s8v bf = *(const s8v*)(bp + ks * 32);
      acca = __builtin_amdgcn_mfma_f32_16x16x32_bf16(a1, bf, acca, 0, 0, 0);
      accm = __builtin_amdgcn_mfma_f32_16x16x32_bf16(a2, bf, accm, 0, 0, 0);
    }
    const int d = d0 + lr;
#pragma unroll
    for (int r = 0; r < 4; ++r) {
      const int R = lk * 4 + r;
      const int grow = bt * C_ + v0 + R;
      const float hv = h[grow * D_ + d];
      const int swz = (R & 7) << 4;
      *(u16*)((char*)at + R * 1024 + ((d * 2) ^ swz)) = bfu(acca[r]);
      *(u16*)((char*)at + R * 1024 + (((256 + d) * 2) ^ swz)) = bfu(accm[r] * hv);
    }
  }
  __syncthreads();

  // ---- k4: 2 col-tiles/wave ----
  const float b1v = be1[0];
#pragma unroll
  for (int i = 0; i < 2; ++i) {
    const int col0 = (widx * 2 + i) * 16;
    const u16* bp = wcatT + (col0 + lr) * 512 + lk * 8;
    f4v acc = {0.f, 0.f, 0.f, 0.f};
#pragma unroll
    for (int ks = 0; ks < 16; ++ks) {
      const int boff = lr * 1024 + ((ks * 64 + lk * 16) ^ ((lr & 7) << 4));
      const s8v af = *(const s8v*)((char*)at + boff);
      const s8v bf = *(const s8v*)(bp + ks * 32);
      acc = __builtin_amdgcn_mfma_f32_16x16x32_bf16(af, bf, acc, 0, 0, 0);
    }
    const int col = col0 + lr;
    const float bc = bcat[col];
#pragma unroll
    for (int r = 0; r < 4; ++r) {
      const int row = bt * C_ + v0 + lk * 4 + r;
      z[row * D_ + col] = acc[r] + b1v * h[row * D_ + col] + bc;
    }
  }
}

extern "C" void kernel_launch(void* const* d_in, const int* in_sizes, int n_in,
                              void* d_out, int out_size, void* d_ws, size_t ws_size,
                              hipStream_t stream) {
  const float* h   = (const float*)d_in[0];
  const float* Aa  = (const float*)d_in[1];
  const float* Am  = (const float*)d_in[2];
  const float* W1  = (const float*)d_in[3];
  const float* b1  = (const float*)d_in[4];
  const float* W2  = (const float*)d_in[5];
  const float* b2  = (const float*)d_in[6];
  const float* Wa  = (const float*)d_in[7];
  const float* ba  = (const float*)d_in[8];
  const float* Wm  = (const float*)d_in[9];
  const float* bm  = (const float*)d_in[10];
  const float* be1 = (const float*)d_in[11];
  const float* be2 = (const float*)d_in[12];
  const float* be3 = (const float*)d_in[13];
  float* z = (float*)d_out;

  char* wsb = (char*)d_ws;
  u16*   w1t   = (u16*)(wsb);                             // 256 KB
  u16*   wcatT = (u16*)(wsb + (256 << 10));               // 256 KB
  u16*   amT   = (u16*)(wsb + (512 << 10));               // 32 KB
  float* bcat  = (float*)(wsb + (544 << 10));             // 1 KB
  u16*   hbT   = (u16*)(wsb + (1 << 20));                 // 1 MB
  u16*   P     = (u16*)(wsb + (2 << 20));                 // 1 MB
  u16*   Q     = (u16*)(wsb + (3 << 20));                 // 1 MB
  u16*   SA    = (u16*)(wsb + (4 << 20));                 // 512 KB [b][v][u]

  kprep  <<<785,  256, 0, stream>>>(h, W1, Wa, Wm, Am, ba, bm, be2, be3,
                                    hbT, w1t, wcatT, amT, bcat);
  k1_mfma<<<1024, 256, 0, stream>>>(h, w1t, b1, P, Q);
  k2_s   <<<dim3(8, 8, 16), 256, 0, stream>>>(P, Q, W2, b2, Aa, SA);
  k34_mfma<<<128, 512, 0, stream>>>(SA, amT, hbT, wcatT, bcat, h, be1, z);
}